// Round 3
// baseline (675.458 us; speedup 1.0000x reference)
//
#include <hip/hip_runtime.h>

typedef __bf16 bf16x8 __attribute__((ext_vector_type(8)));
typedef float  f32x4  __attribute__((ext_vector_type(4)));

#define NH    16
#define SEQ   8192
#define EDIM  64
#define CHK   512
#define WCOLS 15872      // 512 + 15*1024
#define OUT0  8388608    // NH*SEQ*EDIM

#define MFMA(a, b, c) __builtin_amdgcn_mfma_f32_16x16x32_bf16((a), (b), (c), 0, 0, 0)

__global__ __launch_bounds__(512, 2) void chunked_attn_kernel(
    const float* __restrict__ Qg, const float* __restrict__ Kg,
    const float* __restrict__ Vg, float* __restrict__ out)
{
    // K frags: idx = ((t*2+es)*4 + quad)*16 + l16, 8 bf16 each -> 64 KB
    __shared__ __align__(16) __bf16 lds_k[32768];
    // V^T frags: idx = ((st*4+nt)*4 + quad)*16 + l16 -> 64 KB
    __shared__ __align__(16) __bf16 lds_v[32768];
    // per-wave P transpose buffer, 16 rows x stride 40 (pad kills bank conflicts)
    __shared__ __align__(16) __bf16 lds_p[8][640];

    const int tid  = threadIdx.x;
    const int lane = tid & 63;
    const int wv   = tid >> 6;      // 0..7
    const int l16  = lane & 15;
    const int quad = lane >> 4;     // 0..3

    const int h  = blockIdx.x >> 4;
    const int n  = blockIdx.x & 15;
    const int ns = (n == 0) ? 0 : n - 1;   // source chunk for K/V

    const size_t qbase = ((size_t)h * SEQ + (size_t)n  * CHK) * EDIM;
    const size_t kbase = ((size_t)h * SEQ + (size_t)ns * CHK) * EDIM;
    float* __restrict__ W = out + OUT0;
    const size_t wrow0  = (size_t)h * CHK;
    const int    colbase = (n == 0) ? 0 : (CHK + (n - 1) * 2 * CHK);

    // ---- stage K as bf16 in MFMA-B frag-major layout ----
    // (no upfront zero-fill: staging loads must not queue behind 251 MB of
    //  zero stores — vmcnt is in-order and the VMEM queue is finite, so the
    //  old ordering serialized zero-drain before compute. Zeros are emitted
    //  inside the mt loop instead, where MFMA/VALU work hides the drain.)
    #pragma unroll
    for (int it = 0; it < 8; ++it) {
        const int c = tid + it * 512;          // 4096 chunks of 8 elems
        const int s = c >> 3, sub = c & 7;     // sub = es*4 + qd, e0 = sub*8
        const float* src = Kg + kbase + (size_t)s * EDIM + sub * 8;
        const float4 a = *(const float4*)src;
        const float4 b = *(const float4*)(src + 4);
        bf16x8 t;
        t[0] = (__bf16)a.x; t[1] = (__bf16)a.y; t[2] = (__bf16)a.z; t[3] = (__bf16)a.w;
        t[4] = (__bf16)b.x; t[5] = (__bf16)b.y; t[6] = (__bf16)b.z; t[7] = (__bf16)b.w;
        const int idx = ((s >> 4) * 8 + sub) * 16 + (s & 15);
        ((bf16x8*)lds_k)[idx] = t;
    }

    // ---- stage V^T as bf16 frags (coalesced reads along e) ----
    #pragma unroll
    for (int it = 0; it < 8; ++it) {
        const int c = tid + it * 512;
        const int e = c & 63, sb = c >> 6;     // sb = st*4 + qd, s0 = sb*8
        bf16x8 t;
        #pragma unroll
        for (int j = 0; j < 8; ++j)
            t[j] = (__bf16)Vg[kbase + (size_t)(sb * 8 + j) * EDIM + e];
        const int idx = (((sb >> 2) * 4 + (e >> 4)) * 4 + (sb & 3)) * 16 + (e & 15);
        ((bf16x8*)lds_v)[idx] = t;
    }

    __syncthreads();

    const float SC = 0.125f * 1.44269504088896340736f;  // scale * log2(e), folded into Q
    __bf16* const pb = lds_p[wv];
    const bf16x8* const kf = (const bf16x8*)lds_k;
    const bf16x8* const vf = (const bf16x8*)lds_v;
    const size_t z0 = wrow0 * WCOLS + (size_t)(colbase + CHK);

    for (int mt = 0; mt < 4; ++mt) {
        const int m0 = wv * 64 + mt * 16;      // this wave's m-tile base row
        const int rq = m0 + quad * 4;          // C-layout row base for this lane

        // ---- Q A-frags (scaled, bf16) ----
        bf16x8 aq0, aq1;
        {
            const float* qp = Qg + qbase + (size_t)(m0 + l16) * EDIM + quad * 8;
            float4 a = *(const float4*)(qp);
            float4 b = *(const float4*)(qp + 4);
            aq0[0]=(__bf16)(a.x*SC); aq0[1]=(__bf16)(a.y*SC); aq0[2]=(__bf16)(a.z*SC); aq0[3]=(__bf16)(a.w*SC);
            aq0[4]=(__bf16)(b.x*SC); aq0[5]=(__bf16)(b.y*SC); aq0[6]=(__bf16)(b.z*SC); aq0[7]=(__bf16)(b.w*SC);
            a = *(const float4*)(qp + 32);
            b = *(const float4*)(qp + 36);
            aq1[0]=(__bf16)(a.x*SC); aq1[1]=(__bf16)(a.y*SC); aq1[2]=(__bf16)(a.z*SC); aq1[3]=(__bf16)(a.w*SC);
            aq1[4]=(__bf16)(b.x*SC); aq1[5]=(__bf16)(b.y*SC); aq1[6]=(__bf16)(b.z*SC); aq1[7]=(__bf16)(b.w*SC);
        }

        // ---- single QK pass: S stripe resident in registers (masked to -inf) ----
        f32x4 st[32];
        #pragma unroll
        for (int t = 0; t < 32; ++t) {
            const int kb = t * 128 + quad * 16 + l16;
            f32x4 acc = {0.f, 0.f, 0.f, 0.f};
            acc = MFMA(aq0, kf[kb],      acc);
            acc = MFMA(aq1, kf[kb + 64], acc);
            const int col = t * 16 + l16;
            #pragma unroll
            for (int r = 0; r < 4; ++r)
                acc[r] = (col <= rq + r) ? acc[r] : -3.0e38f;
            st[t] = acc;
        }

        // ---- distributed zero-fill of masked half-window (drains during
        //      the pure-VALU softmax phase below) ----
        if (n != 0) {
            #pragma unroll 4
            for (int i = 0; i < 32; ++i) {
                const int idx = (mt * 32 + i) * 512 + tid;
                const int r = idx >> 7, j = idx & 127;
                f32x4 z = {0.f, 0.f, 0.f, 0.f};
                __builtin_nontemporal_store(z, (f32x4*)(W + z0 + (size_t)r * WCOLS + (size_t)(j * 4)));
            }
        }

        // ---- row max (tree fmax, no exp2) ----
        float mr[4];
        #pragma unroll
        for (int r = 0; r < 4; ++r) mr[r] = st[0][r];
        #pragma unroll
        for (int t = 1; t < 32; ++t) {
            #pragma unroll
            for (int r = 0; r < 4; ++r) mr[r] = fmaxf(mr[r], st[t][r]);
        }
        #pragma unroll
        for (int r = 0; r < 4; ++r) {
            #pragma unroll
            for (int off = 1; off < 16; off <<= 1)
                mr[r] = fmaxf(mr[r], __shfl_xor(mr[r], off));
        }

        // ---- exp2 + row sum (one exp2 per element, in place) ----
        float lr[4] = {0.f, 0.f, 0.f, 0.f};
        #pragma unroll
        for (int t = 0; t < 32; ++t) {
            #pragma unroll
            for (int r = 0; r < 4; ++r) {
                const float e = __builtin_amdgcn_exp2f(st[t][r] - mr[r]);
                st[t][r] = e;
                lr[r] += e;
            }
        }
        float ri[4];
        #pragma unroll
        for (int r = 0; r < 4; ++r) {
            #pragma unroll
            for (int off = 1; off < 16; off <<= 1)
                lr[r] += __shfl_xor(lr[r], off);
            ri[r] = __builtin_amdgcn_rcpf(lr[r]);
        }

        // ---- normalize + transpose via per-wave LDS + W store + PV ----
        f32x4 o0 = {0,0,0,0}, o1 = {0,0,0,0}, o2 = {0,0,0,0}, o3 = {0,0,0,0};
        float* const wbase = W + (wrow0 + (size_t)(m0 + l16)) * WCOLS + colbase;
        #pragma unroll
        for (int pr = 0; pr < 16; ++pr) {
            #pragma unroll
            for (int tt = 0; tt < 2; ++tt) {
                const int t = pr * 2 + tt;
                #pragma unroll
                for (int r = 0; r < 4; ++r) {
                    const float p = st[t][r] * ri[r];
                    pb[(quad * 4 + r) * 40 + tt * 16 + l16] = (__bf16)p;
                }
            }
            // C-layout -> A-layout via per-wave LDS (in-wave DS ordering, no barrier)
            const bf16x8 pa = *(const bf16x8*)(pb + l16 * 40 + quad * 8);
            // vectorized weight store: row m0+l16, cols pr*32 + quad*8 .. +7
            {
                f32x4 w0, w1;
                w0[0]=(float)pa[0]; w0[1]=(float)pa[1]; w0[2]=(float)pa[2]; w0[3]=(float)pa[3];
                w1[0]=(float)pa[4]; w1[1]=(float)pa[5]; w1[2]=(float)pa[6]; w1[3]=(float)pa[7];
                float* wp = wbase + pr * 32 + quad * 8;
                __builtin_nontemporal_store(w0, (f32x4*)wp);
                __builtin_nontemporal_store(w1, (f32x4*)(wp + 4));
            }
            const int vb = pr * 256 + quad * 16 + l16;
            o0 = MFMA(pa, vf[vb      ], o0);
            o1 = MFMA(pa, vf[vb +  64], o1);
            o2 = MFMA(pa, vf[vb + 128], o2);
            o3 = MFMA(pa, vf[vb + 192], o3);
        }

        // ---- write O tile ----
        const size_t ob = qbase + (size_t)rq * EDIM + l16;
        #pragma unroll
        for (int r = 0; r < 4; ++r) {
            __builtin_nontemporal_store(o0[r], out + ob + (size_t)r * EDIM     );
            __builtin_nontemporal_store(o1[r], out + ob + (size_t)r * EDIM + 16);
            __builtin_nontemporal_store(o2[r], out + ob + (size_t)r * EDIM + 32);
            __builtin_nontemporal_store(o3[r], out + ob + (size_t)r * EDIM + 48);
        }
    }
}

extern "C" void kernel_launch(void* const* d_in, const int* in_sizes, int n_in,
                              void* d_out, int out_size, void* d_ws, size_t ws_size,
                              hipStream_t stream) {
    const float* Q = (const float*)d_in[0];
    const float* K = (const float*)d_in[1];
    const float* V = (const float*)d_in[2];
    float* out = (float*)d_out;
    chunked_attn_kernel<<<dim3(256), dim3(512), 0, stream>>>(Q, K, V, out);
}

// Round 4
// 632.600 us; speedup vs baseline: 1.0677x; 1.0677x over previous
//
#include <hip/hip_runtime.h>

typedef __bf16 bf16x8 __attribute__((ext_vector_type(8)));
typedef float  f32x4  __attribute__((ext_vector_type(4)));

#define NH    16
#define SEQ   8192
#define EDIM  64
#define CHK   512
#define WCOLS 15872      // 512 + 15*1024
#define OUT0  8388608    // NH*SEQ*EDIM

#define MFMA(a, b, c) __builtin_amdgcn_mfma_f32_16x16x32_bf16((a), (b), (c), 0, 0, 0)

// ---------------------------------------------------------------------------
// Kernel A: zero the masked half-windows. Fully-coalesced linear stores
// (1 KB contiguous per wave-instr), 2048 blocks -> runs at fill rate.
// Zero cols for chunk n (n>=1) are exactly [n*1024, n*1024+512) of rows
// h*512..h*512+511.  Total 15*16*512*512 f32 = 251.7 MB.
// ---------------------------------------------------------------------------
__global__ __launch_bounds__(256) void zero_fill_kernel(float* __restrict__ W) {
    const int gid = blockIdx.x * 256 + threadIdx.x;   // 524288 threads
    #pragma unroll
    for (int it = 0; it < 30; ++it) {                 // 524288*30 = 15728640 x4-units
        const int i     = gid + it * 524288;
        const int j     = i & 127;                    // x4-unit within row (128 = 512 f32)
        const int rowid = i >> 7;
        const int r     = rowid & 511;
        const int w     = rowid >> 9;                 // 0..239 = h*15 + (n-1)
        const int h     = w / 15;
        const int n     = w - h * 15 + 1;             // 1..15
        float* p = W + (size_t)(h * 512 + r) * WCOLS + (size_t)n * 1024 + j * 4;
        f32x4 z = {0.f, 0.f, 0.f, 0.f};
        __builtin_nontemporal_store(z, (f32x4*)p);
    }
}

// ---------------------------------------------------------------------------
// Kernel B: chunked attention. One block per (h, chunk).
// ---------------------------------------------------------------------------
__global__ __launch_bounds__(512, 2) void chunked_attn_kernel(
    const float* __restrict__ Qg, const float* __restrict__ Kg,
    const float* __restrict__ Vg, float* __restrict__ out)
{
    // K frags: idx = ((t*2+es)*4 + quad)*16 + l16, 8 bf16 each -> 64 KB
    __shared__ __align__(16) __bf16 lds_k[32768];
    // V^T frags: idx = ((st*4+nt)*4 + quad)*16 + l16 -> 64 KB
    __shared__ __align__(16) __bf16 lds_v[32768];
    // per-wave P transpose buffer, 16 rows x stride 40 (pad kills bank conflicts)
    __shared__ __align__(16) __bf16 lds_p[8][640];

    const int tid  = threadIdx.x;
    const int lane = tid & 63;
    const int wv   = tid >> 6;      // 0..7
    const int l16  = lane & 15;
    const int quad = lane >> 4;     // 0..3

    const int h  = blockIdx.x >> 4;
    const int n  = blockIdx.x & 15;
    const int ns = (n == 0) ? 0 : n - 1;   // source chunk for K/V

    const size_t qbase = ((size_t)h * SEQ + (size_t)n  * CHK) * EDIM;
    const size_t kbase = ((size_t)h * SEQ + (size_t)ns * CHK) * EDIM;
    float* __restrict__ W = out + OUT0;
    const size_t wrow0  = (size_t)h * CHK;
    const int    colbase = (n == 0) ? 0 : (CHK + (n - 1) * 2 * CHK);

    // ---- stage K as bf16 in MFMA-B frag-major layout ----
    #pragma unroll
    for (int it = 0; it < 8; ++it) {
        const int c = tid + it * 512;          // 4096 chunks of 8 elems
        const int s = c >> 3, sub = c & 7;     // sub = es*4 + qd, e0 = sub*8
        const float* src = Kg + kbase + (size_t)s * EDIM + sub * 8;
        const float4 a = *(const float4*)src;
        const float4 b = *(const float4*)(src + 4);
        bf16x8 t;
        t[0] = (__bf16)a.x; t[1] = (__bf16)a.y; t[2] = (__bf16)a.z; t[3] = (__bf16)a.w;
        t[4] = (__bf16)b.x; t[5] = (__bf16)b.y; t[6] = (__bf16)b.z; t[7] = (__bf16)b.w;
        const int idx = ((s >> 4) * 8 + sub) * 16 + (s & 15);
        ((bf16x8*)lds_k)[idx] = t;
    }

    // ---- stage V^T as bf16 frags (coalesced reads along e) ----
    #pragma unroll
    for (int it = 0; it < 8; ++it) {
        const int c = tid + it * 512;
        const int e = c & 63, sb = c >> 6;     // sb = st*4 + qd, s0 = sb*8
        bf16x8 t;
        #pragma unroll
        for (int j = 0; j < 8; ++j)
            t[j] = (__bf16)Vg[kbase + (size_t)(sb * 8 + j) * EDIM + e];
        const int idx = (((sb >> 2) * 4 + (e >> 4)) * 4 + (sb & 3)) * 16 + (e & 15);
        ((bf16x8*)lds_v)[idx] = t;
    }

    __syncthreads();

    const float SC = 0.125f * 1.44269504088896340736f;  // scale * log2(e), folded into Q
    __bf16* const pb = lds_p[wv];
    const bf16x8* const kf = (const bf16x8*)lds_k;
    const bf16x8* const vf = (const bf16x8*)lds_v;

    for (int mt = 0; mt < 4; ++mt) {
        const int m0 = wv * 64 + mt * 16;      // this wave's m-tile base row
        const int rq = m0 + quad * 4;          // C-layout row base for this lane

        // ---- Q A-frags (scaled, bf16) ----
        bf16x8 aq0, aq1;
        {
            const float* qp = Qg + qbase + (size_t)(m0 + l16) * EDIM + quad * 8;
            float4 a = *(const float4*)(qp);
            float4 b = *(const float4*)(qp + 4);
            aq0[0]=(__bf16)(a.x*SC); aq0[1]=(__bf16)(a.y*SC); aq0[2]=(__bf16)(a.z*SC); aq0[3]=(__bf16)(a.w*SC);
            aq0[4]=(__bf16)(b.x*SC); aq0[5]=(__bf16)(b.y*SC); aq0[6]=(__bf16)(b.z*SC); aq0[7]=(__bf16)(b.w*SC);
            a = *(const float4*)(qp + 32);
            b = *(const float4*)(qp + 36);
            aq1[0]=(__bf16)(a.x*SC); aq1[1]=(__bf16)(a.y*SC); aq1[2]=(__bf16)(a.z*SC); aq1[3]=(__bf16)(a.w*SC);
            aq1[4]=(__bf16)(b.x*SC); aq1[5]=(__bf16)(b.y*SC); aq1[6]=(__bf16)(b.z*SC); aq1[7]=(__bf16)(b.w*SC);
        }

        // ---- single QK pass: S stripe resident in registers (masked to -inf) ----
        f32x4 st[32];
        #pragma unroll
        for (int t = 0; t < 32; ++t) {
            const int kb = t * 128 + quad * 16 + l16;
            f32x4 acc = {0.f, 0.f, 0.f, 0.f};
            acc = MFMA(aq0, kf[kb],      acc);
            acc = MFMA(aq1, kf[kb + 64], acc);
            const int col = t * 16 + l16;
            #pragma unroll
            for (int r = 0; r < 4; ++r)
                acc[r] = (col <= rq + r) ? acc[r] : -3.0e38f;
            st[t] = acc;
        }

        // ---- row max (tree fmax, no exp2) ----
        float mr[4];
        #pragma unroll
        for (int r = 0; r < 4; ++r) mr[r] = st[0][r];
        #pragma unroll
        for (int t = 1; t < 32; ++t) {
            #pragma unroll
            for (int r = 0; r < 4; ++r) mr[r] = fmaxf(mr[r], st[t][r]);
        }
        #pragma unroll
        for (int r = 0; r < 4; ++r) {
            #pragma unroll
            for (int off = 1; off < 16; off <<= 1)
                mr[r] = fmaxf(mr[r], __shfl_xor(mr[r], off));
        }

        // ---- exp2 + row sum (one exp2 per element, in place) ----
        // masked entries: exp2(-3e38 - mr) == 0 exactly -> weights store exact 0
        float lr[4] = {0.f, 0.f, 0.f, 0.f};
        #pragma unroll
        for (int t = 0; t < 32; ++t) {
            #pragma unroll
            for (int r = 0; r < 4; ++r) {
                const float e = __builtin_amdgcn_exp2f(st[t][r] - mr[r]);
                st[t][r] = e;
                lr[r] += e;
            }
        }
        float ri[4];
        #pragma unroll
        for (int r = 0; r < 4; ++r) {
            #pragma unroll
            for (int off = 1; off < 16; off <<= 1)
                lr[r] += __shfl_xor(lr[r], off);
            ri[r] = __builtin_amdgcn_rcpf(lr[r]);
        }

        // ---- W store burst, straight from C-layout registers ----
        // col = t*16 + l16: 16 lanes -> one 64-B full sector; 4 rows (quads)
        // per instruction. Full f32 precision. Issued before the PV loop so
        // the drain overlaps the LDS/MFMA work below.
        {
            float* const wp0 = W + (wrow0 + (size_t)rq) * WCOLS + colbase + l16;
            #pragma unroll
            for (int t = 0; t < 32; ++t) {
                #pragma unroll
                for (int r = 0; r < 4; ++r)
                    __builtin_nontemporal_store(st[t][r] * ri[r],
                        wp0 + (size_t)r * WCOLS + t * 16);
            }
        }

        // ---- normalize + transpose via per-wave LDS + PV ----
        f32x4 o0 = {0,0,0,0}, o1 = {0,0,0,0}, o2 = {0,0,0,0}, o3 = {0,0,0,0};
        #pragma unroll
        for (int pr = 0; pr < 16; ++pr) {
            #pragma unroll
            for (int tt = 0; tt < 2; ++tt) {
                const int t = pr * 2 + tt;
                #pragma unroll
                for (int r = 0; r < 4; ++r) {
                    const float p = st[t][r] * ri[r];
                    pb[(quad * 4 + r) * 40 + tt * 16 + l16] = (__bf16)p;
                }
            }
            // C-layout -> A-layout via per-wave LDS (in-wave DS ordering, no barrier)
            const bf16x8 pa = *(const bf16x8*)(pb + l16 * 40 + quad * 8);
            const int vb = pr * 256 + quad * 16 + l16;
            o0 = MFMA(pa, vf[vb      ], o0);
            o1 = MFMA(pa, vf[vb +  64], o1);
            o2 = MFMA(pa, vf[vb + 128], o2);
            o3 = MFMA(pa, vf[vb + 192], o3);
        }

        // ---- write O tile (64-B sectors per quad-row) ----
        const size_t ob = qbase + (size_t)rq * EDIM + l16;
        #pragma unroll
        for (int r = 0; r < 4; ++r) {
            __builtin_nontemporal_store(o0[r], out + ob + (size_t)r * EDIM     );
            __builtin_nontemporal_store(o1[r], out + ob + (size_t)r * EDIM + 16);
            __builtin_nontemporal_store(o2[r], out + ob + (size_t)r * EDIM + 32);
            __builtin_nontemporal_store(o3[r], out + ob + (size_t)r * EDIM + 48);
        }
    }
}

extern "C" void kernel_launch(void* const* d_in, const int* in_sizes, int n_in,
                              void* d_out, int out_size, void* d_ws, size_t ws_size,
                              hipStream_t stream) {
    const float* Q = (const float*)d_in[0];
    const float* K = (const float*)d_in[1];
    const float* V = (const float*)d_in[2];
    float* out = (float*)d_out;
    zero_fill_kernel<<<dim3(2048), dim3(256), 0, stream>>>(out + OUT0);
    chunked_attn_kernel<<<dim3(256), dim3(512), 0, stream>>>(Q, K, V, out);
}